// Round 6
// baseline (3959.927 us; speedup 1.0000x reference)
//
#include <hip/hip_runtime.h>
#include <math.h>

#define T_TOTAL 262144
#define HID 32
#define WIN 2048                      /* windows: 128 serial steps each */
#define WLEN (T_TOTAL / WIN)          /* 128 steps per window */
#define NSWEEP 8                      /* total sweeps; NSWEEP-1 corrections */
#define FD_EPS0 4.0                   /* FD perturbation on s0 (snow) */
#define FD_EPS1 8.0                   /* FD perturbation on s1 (water) */
#define LOG2E 1.4426950408889634f
#define TANH2C 2.8853900817779268f    /* 2*log2e */
#define NEG10LOG2E (-14.426950408889634f)
#define POS10LOG2E (14.426950408889634f)

#define PIN(x) asm volatile("" : "+v"(x))

typedef _Float16 f16x8 __attribute__((ext_vector_type(8)));
typedef float f32x4 __attribute__((ext_vector_type(4)));

__device__ __forceinline__ float fexp2(float x) { return __builtin_amdgcn_exp2f(x); }
__device__ __forceinline__ float frcp(float x)  { return __builtin_amdgcn_rcpf(x); }
__device__ __forceinline__ float fast_sig10(float x) {
    return frcp(1.0f + fexp2(x * NEG10LOG2E));
}
__device__ __forceinline__ float fast_tanh_clamp(float x) { // out_kernel only
    float xc = __builtin_amdgcn_fmed3f(x, -9.0f, 9.0f);
    float u  = fexp2(xc * TANH2C);
    return fmaf(-2.0f, frcp(u + 1.0f), 1.0f);
}
__device__ __forceinline__ float fast_tanh_nc(float x) {
    float u = fexp2(x * TANH2C);
    return fmaf(-2.0f, frcp(u + 1.0f), 1.0f);
}

// ---- DPP / lane helpers ----------------------------------------------------
template <int CTRL>
__device__ __forceinline__ float dpp_add(float v) {
    int t = __builtin_amdgcn_update_dpp(0, __float_as_int(v), CTRL, 0xF, 0xF, true);
    return v + __int_as_float(t);
}
__device__ __forceinline__ float allsum16(float x) {
    x = dpp_add<0xB1>(x);   // quad_perm xor1
    x = dpp_add<0x4E>(x);   // quad_perm xor2
    x = dpp_add<0x141>(x);  // row_half_mirror
    x = dpp_add<0x140>(x);  // row_mirror
    return x;
}
__device__ __forceinline__ int dpp_xor1_i(int v) {
    return __builtin_amdgcn_update_dpp(0, v, 0xB1, 0xF, 0xF, true);
}
__device__ __forceinline__ float rl(float x, int lane) {
    return __int_as_float(__builtin_amdgcn_readlane(__float_as_int(x), lane));
}
__device__ __forceinline__ float bpf(int addr, float x) {
    return __int_as_float(__builtin_amdgcn_ds_bpermute(addr, __float_as_int(x)));
}

// ---------------------------------------------------------------------------
// init: all window ICs = global Y0 guess
// ---------------------------------------------------------------------------
__global__ void init_kernel(const float* __restrict__ inputs, double2* icg) {
    int w = blockIdx.x * blockDim.x + threadIdx.x;
    if (w < WIN) icg[w] = make_double2((double)inputs[0], (double)inputs[1]);
}

// ---------------------------------------------------------------------------
// Newton-Parareal sweep, FOUR trajectory slots per wave (3 used):
//   quad 0 = unperturbed, quad 1 = +FD_EPS0 on s0, quads 2,3 = +FD_EPS1 on s1
//   (quad 3 duplicates quad 2 — C-rows 2,3 mod 4 read identical packed h1).
// Layer-1: every lane computes h1 for its half's primary traj (A for lanes
//   0-31, B for 32-63; states broadcast via readlane) AND for traj C.
//   Packed f16 words: traj A at even lanes 0-31, B at even lanes 32-63,
//   C at odd lanes (odd lanes' words were unused in the 2-traj scheme).
//   A-fragment row class r&3 in {0,1,2,3} gathers from {+0,+128,+4,+132}.
//   The same 4 MFMAs then serve all three trajectories (C rows 4q+0..3).
// Layer-3: each quad computes its own trajectory's 5 output channels
//   (cols 0-4) + 4 sigmoid slots (cols 5-8: s0, s1, tm_mid, tm_end);
//   per-quad ds_bpermute gathers at base 64*quad; stm recurrence reads
//   quad-0 cols 7,8 via readlane (wave-uniform forcing).
// Unperturbed path is arithmetically identical to the verified R4 kernel.
// Launch: WIN blocks for ALL sweeps (J and final) = 2 waves/SIMD.
// ---------------------------------------------------------------------------
__global__ __launch_bounds__(64, 1) void sweep_kernel(
    const float* __restrict__ inputs,   // (T,5)
    const float* __restrict__ lday,     // (T,)
    const float* __restrict__ W1, const float* __restrict__ b1,
    const float* __restrict__ W2, const float* __restrict__ b2,
    const float* __restrict__ W3, const float* __restrict__ b3,
    float* __restrict__ traj,           // (T,2)
    const double2* __restrict__ icg,    // window ICs (read)
    double2* __restrict__ E)            // end states (write), 3*WIN
{
    const int lane = threadIdx.x;
    const int col  = lane & 15;
    const int quad = lane >> 4;
    const int j32  = lane & 31;
    const int half = lane >> 5;
    const bool odd = (lane & 1) != 0;

    const int wnd  = blockIdx.x;
    const int S    = wnd * WLEN;
    const int endStep = (S + WLEN < T_TOTAL - 1) ? (S + WLEN) : (T_TOTAL - 1);

    // layer-1 weights, pre-scaled by 2log2e
    float w1c0 = W1[0 * HID + j32] * TANH2C, w1c1 = W1[1 * HID + j32] * TANH2C;
    float w1c2 = W1[2 * HID + j32] * TANH2C, w1c3 = W1[3 * HID + j32] * TANH2C;
    float b1j = b1[j32] * TANH2C;
    PIN(w1c0); PIN(w1c1); PIN(w1c2); PIN(w1c3); PIN(b1j);

    // W2*2log2e as f16 hi/lo B-fragments
    f16x8 Bhi0, Blo0, Bhi1, Blo1;
#pragma unroll
    for (int jj = 0; jj < 8; ++jj) {
        float w0 = W2[(quad * 8 + jj) * HID + col] * TANH2C;
        float w1v = W2[(quad * 8 + jj) * HID + col + 16] * TANH2C;
        _Float16 h0 = (_Float16)w0, h1v = (_Float16)w1v;
        Bhi0[jj] = h0;  Blo0[jj] = (_Float16)(w0 - (float)h0);
        Bhi1[jj] = h1v; Blo1[jj] = (_Float16)(w1v - (float)h1v);
    }
    PIN(Bhi0); PIN(Blo0); PIN(Bhi1); PIN(Blo1);

    float b2a2 = b2[col] * TANH2C, b2b2 = b2[col + 16] * TANH2C;
    f32x4 cb0 = {b2a2, b2a2, b2a2, b2a2};
    f32x4 cb1 = {b2b2, b2b2, b2b2, b2b2};
    PIN(cb0); PIN(cb1);

    // layer-3 weights: 5 channels per 16-lane quad
    float wca[5], wcb[5];
#pragma unroll
    for (int c = 0; c < 5; ++c) {
        wca[c] = W3[col * 5 + c] * LOG2E;
        wcb[c] = W3[(col + 16) * 5 + c] * LOG2E;
        PIN(wca[c]); PIN(wcb[c]);
    }

    float m0 = (col == 0) ? 1.f : 0.f;
    float m1 = (col == 1) ? 1.f : 0.f;
    float m2 = (col == 2) ? 1.f : 0.f;
    float m3 = (col == 3) ? 1.f : 0.f;
    float m4 = (col == 4) ? 1.f : 0.f;
    float m5 = (col == 5) ? 1.f : 0.f;
    float m6 = (col == 6) ? 1.f : 0.f;
    float m7 = (col == 7) ? 1.f : 0.f;
    float m8 = (col == 8) ? 1.f : 0.f;
    float sig1m = (col >= 5 && col <= 8) ? 1.f : 0.f;
    float zb = b3[(col < 5) ? col : 0];
    float zconst = (col < 5) ? zb * LOG2E : 0.f;
    PIN(m0); PIN(m1); PIN(m2); PIN(m3); PIN(m4); PIN(m5); PIN(m6); PIN(m7); PIN(m8);
    PIN(sig1m); PIN(zconst);

    int psel = (lane & 1) ? 0x01000504 : 0x05040100;
    // A-build gather base by row class r&3: {A,B,C,C-dup} -> {+0,+128,+4,+132}
    int l3 = lane & 3;
    int roff = (l3 == 1) ? 128 : (l3 == 2) ? 4 : (l3 == 3) ? 132 : 0;
    int bbase = 32 * quad + roff;
    int bp0 = bbase, bp1 = bbase + 8, bp2 = bbase + 16, bp3 = bbase + 24;
    PIN(psel); PIN(bp0); PIN(bp1); PIN(bp2); PIN(bp3);

    // per-quad output-gather addresses (bytes)
    int qb = 64 * quad;
    int a_sh0 = qb + 0,  a_sh1 = qb + 4,  a_sh2 = qb + 8;
    int a_e3  = qb + 12, a_e4  = qb + 16, a_sg0 = qb + 20, a_sg1 = qb + 24;
    PIN(a_sh0); PIN(a_sh1); PIN(a_sh2); PIN(a_e3); PIN(a_e4); PIN(a_sg0); PIN(a_sg1);

    double2 ic = icg[wnd];
    double y0 = ic.x + ((quad == 1) ? FD_EPS0 : 0.0);
    double y1 = ic.y + ((quad >= 2) ? FD_EPS1 : 0.0);
    float2* traj2 = (float2*)traj;
    if (lane == 0 && wnd == 0)
        traj2[0] = make_float2((float)ic.x, (float)ic.y);

    auto rhs = [&](float s0q, float s1q, float base, float stm, float ld, float zoffk,
                   float& d0, float& d1, float& rout) {
        // broadcast the three trajectory states for layer-1
        float s0A = rl(s0q, 0),  s1A = rl(s1q, 0);
        float s0B = rl(s0q, 16), s1B = rl(s1q, 16);
        float s0C = rl(s0q, 32), s1C = rl(s1q, 32);
        float s0p = half ? s0B : s0A;
        float s1p = half ? s1B : s1A;
        // layer-1: primary (A/B by half) and C (all lanes)
        float prep = fmaf(s1p, w1c1, fmaf(s0p, w1c0, base));
        float prec = fmaf(s1C, w1c1, fmaf(s0C, w1c0, base));
        float up_ = fexp2(prep);
        float uc_ = fexp2(prec);
        float h1p = fmaf(-2.0f, frcp(up_ + 1.0f), 1.0f);
        float h1c = fmaf(-2.0f, frcp(uc_ + 1.0f), 1.0f);
        union { _Float16 h; unsigned short u; } cvp, cvc;
        cvp.h = (_Float16)h1p; cvc.h = (_Float16)h1c;
        int ownp = (int)cvp.u, ownc = (int)cvc.u;
        int nbp = dpp_xor1_i(ownp), nbc = dpp_xor1_i(ownc);
        int pkp = __builtin_amdgcn_perm(nbp, ownp, psel);
        int pkc = __builtin_amdgcn_perm(nbc, ownc, psel);
        int pk  = odd ? pkc : pkp;
        int g0i = __builtin_amdgcn_ds_bpermute(bp0, pk);
        int g1i = __builtin_amdgcn_ds_bpermute(bp1, pk);
        int g2i = __builtin_amdgcn_ds_bpermute(bp2, pk);
        int g3i = __builtin_amdgcn_ds_bpermute(bp3, pk);
        union { int i[4]; f16x8 h; } au;
        au.i[0] = g0i; au.i[1] = g1i; au.i[2] = g2i; au.i[3] = g3i;
        f16x8 A = au.h;
        f32x4 zz = {0.f, 0.f, 0.f, 0.f};
        f32x4 chi0 = __builtin_amdgcn_mfma_f32_16x16x32_f16(A, Bhi0, cb0, 0, 0, 0);
        f32x4 clo0 = __builtin_amdgcn_mfma_f32_16x16x32_f16(A, Blo0, zz, 0, 0, 0);
        f32x4 chi1 = __builtin_amdgcn_mfma_f32_16x16x32_f16(A, Bhi1, cb1, 0, 0, 0);
        f32x4 clo1 = __builtin_amdgcn_mfma_f32_16x16x32_f16(A, Blo1, zz, 0, 0, 0);
        // per-quad trajectory row select (C rows: 4q+0=A, +1=B, +2=C, +3=C-dup)
        float tA0 = chi0[0] + clo0[0], tB0 = chi0[1] + clo0[1], tC0 = chi0[2] + clo0[2];
        float tA1 = chi1[0] + clo1[0], tB1 = chi1[1] + clo1[1], tC1 = chi1[2] + clo1[2];
        float t0 = (quad == 1) ? tB0 : (quad >= 2) ? tC0 : tA0;
        float t1 = (quad == 1) ? tB1 : (quad >= 2) ? tC1 : tA1;
        float ua = fexp2(t0);
        float ub = fexp2(t1);
        float g0 = fmaf(-2.0f, frcp(ua + 1.0f), 1.0f);
        float g1 = fmaf(-2.0f, frcp(ub + 1.0f), 1.0f);
        float r0 = fmaf(g0, wca[0], g1 * wcb[0]);
        float r1 = fmaf(g0, wca[1], g1 * wcb[1]);
        float r2 = fmaf(g0, wca[2], g1 * wcb[2]);
        float r3 = fmaf(g0, wca[3], g1 * wcb[3]);
        float r4 = fmaf(g0, wca[4], g1 * wcb[4]);
        float s0r = allsum16(r0);
        float s1r = allsum16(r1);
        float s2r = allsum16(r2);
        float s3r = allsum16(r3);
        float s4r = allsum16(r4);
        float zs0 = s0q * NEG10LOG2E;           // own quad's trajectory
        float zs1 = s1q * NEG10LOG2E;
        float zoff = fmaf(zs0, m5, fmaf(zs1, m6, zoffk));
        float zarg = fmaf(s0r, m0, fmaf(s1r, m1, fmaf(s2r, m2,
                     fmaf(s3r, m3, fmaf(s4r, m4, zoff)))));
        float u = fexp2(zarg);
        float r = frcp(u + sig1m);
        float w = fmaf(0.5f, u, -0.5f * r);
        float sh0 = bpf(a_sh0, w), sh1 = bpf(a_sh1, w), sh2 = bpf(a_sh2, w);
        float e3  = bpf(a_e3, u),  e4  = bpf(a_e4, u);
        float sg0 = bpf(a_sg0, r), sg1 = bpf(a_sg1, r);
        float p_snow = fmaxf(sh0 * stm, 0.f);
        float p_rain = fmaxf(sh1, 0.f);
        float melt   = fmaxf(sg0 * sh2, 0.f);
        float etq    = sg1 * fmaf(e3, ld, e4);
        d0 = p_snow - melt;
        d1 = (p_rain + melt) - etq;
        rout = r;
    };

    float pA = inputs[S * 5 + 2],       tmA = inputs[S * 5 + 3],       ldA = lday[S];
    float pB = inputs[(S + 1) * 5 + 2], tmB = inputs[(S + 1) * 5 + 3], ldB = lday[S + 1];
    float pC = inputs[(S + 2) * 5 + 2], tmC = inputs[(S + 2) * 5 + 3], ldC = lday[S + 2];
    float stmA = fast_sig10(-tmA);
    float stmB = fast_sig10(-tmB);
    float stmm = fast_sig10(-0.5f * (tmA + tmB));
    float baseA = fmaf(pA, w1c2, fmaf(tmA, w1c3, b1j));
    float baseB = fmaf(pB, w1c2, fmaf(tmB, w1c3, b1j));

    for (int n = S; n < endStep; ++n) {
        const float ldm = 0.5f * (ldA + ldB);
        const float pm  = 0.5f * (pA + pB);
        const float tmm = 0.5f * (tmA + tmB);
        const float basem = fmaf(pm, w1c2, fmaf(tmm, w1c3, b1j));
        const float ztm_m = (0.5f * (tmB + tmC)) * POS10LOG2E;
        const float ztm_b = tmC * POS10LOG2E;
        const float zoffk = fmaf(ztm_m, m7, fmaf(ztm_b, m8, zconst));

        const float fy0 = (float)y0, fy1 = (float)y1;
        float k10, k11, k20, k21, k30, k31, k40, k41, rd;
        rhs(fy0,                  fy1,                  baseA, stmA, ldA, zoffk, k10, k11, rd);
        rhs(fmaf(0.5f, k10, fy0), fmaf(0.5f, k11, fy1), basem, stmm, ldm, zoffk, k20, k21, rd);
        rhs(fmaf(0.5f, k20, fy0), fmaf(0.5f, k21, fy1), basem, stmm, ldm, zoffk, k30, k31, rd);
        rhs(fy0 + k30,            fy1 + k31,            baseB, stmB, ldB, zoffk, k40, k41, rd);
        const float stmm_n = rl(rd, 7);
        const float stmB_n = rl(rd, 8);

        const float s0sum = (k10 + 2.0f * k20) + (2.0f * k30 + k40);
        const float s1sum = (k11 + 2.0f * k21) + (2.0f * k31 + k41);
        y0 += (1.0 / 6.0) * (double)s0sum;
        y1 += (1.0 / 6.0) * (double)s1sum;

        if (lane == 0)
            traj2[n + 1] = make_float2((float)y0, (float)y1);

        stmA = stmB; stmB = stmB_n; stmm = stmm_n;
        baseA = baseB;
        baseB = fmaf(pC, w1c2, fmaf(tmC, w1c3, b1j));
        pA = pB; tmA = tmB; ldA = ldB;
        pB = pC; tmB = tmC; ldB = ldC;
        const int np3 = (n + 3 < T_TOTAL) ? (n + 3) : (T_TOTAL - 1);
        pC = inputs[np3 * 5 + 2]; tmC = inputs[np3 * 5 + 3]; ldC = lday[np3];
    }

    if (lane == 0)  E[wnd]           = make_double2(y0, y1);  // unperturbed
    if (lane == 16) E[WIN + wnd]     = make_double2(y0, y1);  // +eps0 on s0
    if (lane == 32) E[2 * WIN + wnd] = make_double2(y0, y1);  // +eps1 on s1
}

// ---------------------------------------------------------------------------
// Sequential Newton-Parareal correction, float-LDS-staged (56 KB).
// Clamps WIDE-OPEN for WLEN=128: short windows barely contract, and snow can
// locally self-amplify (true J00 > 1) — R1/R5 failures (absmax ~2.2) were
// binding upper clamps destroying the Newton contraction. Floors kept only
// to reject FD-noise sign flips.  J01 := 0.
// ---------------------------------------------------------------------------
__global__ __launch_bounds__(64) void correct_kernel(
    const float* __restrict__ inputs,
    const double2* __restrict__ E,
    double2* __restrict__ icg) {
    __shared__ float sE0x[WIN], sE0y[WIN];
    __shared__ float sE1x[WIN], sE1y[WIN];
    __shared__ float sE2y[WIN];
    __shared__ float sGx[WIN], sGy[WIN];
    for (int i = threadIdx.x; i < WIN; i += 64) {
        double2 e0 = E[i];           sE0x[i] = (float)e0.x; sE0y[i] = (float)e0.y;
        double2 e1 = E[WIN + i];     sE1x[i] = (float)e1.x; sE1y[i] = (float)e1.y;
        double2 e2 = E[2 * WIN + i]; sE2y[i] = (float)e2.y;
        double2 g  = icg[i];         sGx[i]  = (float)g.x;  sGy[i]  = (float)g.y;
    }
    __syncthreads();
    if (threadIdx.x != 0) return;

    double y0c = (double)inputs[0];
    double y1c = (double)inputs[1];
    for (int w = 0; w < WIN; ++w) {
        double d0 = y0c - (double)sGx[w];
        double d1 = y1c - (double)sGy[w];
        d0 = fmin(fmax(d0, -50.0), 50.0);      // trust region
        d1 = fmin(fmax(d1, -400.0), 400.0);
        icg[w] = make_double2(y0c, y1c);
        double e0x = (double)sE0x[w], e0y = (double)sE0y[w];
        double J00 = ((double)sE1x[w] - e0x) * (1.0 / FD_EPS0);
        double J10 = ((double)sE1y[w] - e0y) * (1.0 / FD_EPS0);
        double J11 = ((double)sE2y[w] - e0y) * (1.0 / FD_EPS1);
        J00 = fmin(fmax(J00, -0.15), 1.15);    // wide-open for 128-step windows
        J10 = fmin(fmax(J10, -0.30), 1.80);
        J11 = fmin(fmax(J11,  0.00), 1.10);
        y0c = e0x + J00 * d0;                  // J01 = 0
        y1c = e0y + J10 * d0 + J11 * d1;
        y0c = fmin(fmax(y0c, -5.0), 1000.0);   // physical sanity
        y1c = fmin(fmax(y1c, -5.0), 5000.0);
    }
}

// ---------------------------------------------------------------------------
// Parallel readout: out[t] = mlp(relu(state), p, tm)[4]
// ---------------------------------------------------------------------------
__global__ __launch_bounds__(256) void out_kernel(
    const float* __restrict__ inputs,
    const float* __restrict__ traj,
    const float* __restrict__ W1, const float* __restrict__ b1,
    const float* __restrict__ W2, const float* __restrict__ b2,
    const float* __restrict__ W3, const float* __restrict__ b3,
    float* __restrict__ out)
{
    __shared__ float sW1[4 * HID];
    __shared__ float sb1[HID];
    __shared__ float sW2T[HID * HID];
    __shared__ float sb2[HID];
    __shared__ float sw3[HID];
    for (int i = threadIdx.x; i < 4 * HID; i += 256) sW1[i] = W1[i];
    for (int i = threadIdx.x; i < HID; i += 256) {
        sb1[i] = b1[i]; sb2[i] = b2[i]; sw3[i] = W3[i * 5 + 4];
    }
    for (int idx = threadIdx.x; idx < HID * HID; idx += 256) {
        int jj = idx >> 5, ii = idx & 31;
        sW2T[idx] = W2[ii * HID + jj];
    }
    __syncthreads();

    int t = blockIdx.x * 256 + threadIdx.x;
    if (t >= T_TOTAL) return;

    float2 st = ((const float2*)traj)[t];
    float s0 = fmaxf(st.x, 0.0f);
    float s1 = fmaxf(st.y, 0.0f);
    float p  = inputs[t * 5 + 2];
    float tm = inputs[t * 5 + 3];

    float h1[HID];
#pragma unroll
    for (int jj = 0; jj < HID; ++jj) {
        float pre = fmaf(s0, sW1[jj], fmaf(s1, sW1[HID + jj],
                    fmaf(p, sW1[2 * HID + jj],
                    fmaf(tm, sW1[3 * HID + jj], sb1[jj]))));
        h1[jj] = fast_tanh_clamp(pre);
    }
    float o = b3[4];
#pragma unroll 4
    for (int jj = 0; jj < HID; ++jj) {
        float a0 = sb2[jj], a1 = 0.f, a2 = 0.f, a3 = 0.f;
#pragma unroll
        for (int ii = 0; ii < HID; ii += 4) {
            a0 = fmaf(h1[ii + 0], sW2T[jj * HID + ii + 0], a0);
            a1 = fmaf(h1[ii + 1], sW2T[jj * HID + ii + 1], a1);
            a2 = fmaf(h1[ii + 2], sW2T[jj * HID + ii + 2], a2);
            a3 = fmaf(h1[ii + 3], sW2T[jj * HID + ii + 3], a3);
        }
        o = fmaf(fast_tanh_nc((a0 + a1) + (a2 + a3)), sw3[jj], o);
    }
    out[t] = o;
}

extern "C" void kernel_launch(void* const* d_in, const int* in_sizes, int n_in,
                              void* d_out, int out_size, void* d_ws, size_t ws_size,
                              hipStream_t stream) {
    (void)in_sizes; (void)n_in; (void)out_size; (void)ws_size;
    const float* inputs = (const float*)d_in[0];
    const float* lday   = (const float*)d_in[1];
    const float* W1     = (const float*)d_in[2];
    const float* b1     = (const float*)d_in[3];
    const float* W2     = (const float*)d_in[4];
    const float* b2     = (const float*)d_in[5];
    const float* W3     = (const float*)d_in[6];
    const float* b3     = (const float*)d_in[7];
    float* out  = (float*)d_out;
    float* traj = (float*)d_ws;                 // T*2 floats = 2 MB

    // small Parareal arrays live in d_out (scratch until out_kernel)
    // E = 3*WIN double2 = 96 KB at offset 0; icg = WIN double2 = 32 KB at +128 KB
    char* scr = (char*)d_out;
    double2* E   = (double2*)scr;
    double2* icg = (double2*)(scr + 131072);

    hipLaunchKernelGGL(init_kernel, dim3((WIN + 255) / 256), dim3(256), 0, stream,
                       inputs, icg);
    for (int k = 0; k < NSWEEP - 1; ++k) {
        hipLaunchKernelGGL(sweep_kernel, dim3(WIN), dim3(64), 0, stream,
                           inputs, lday, W1, b1, W2, b2, W3, b3, traj, icg, E);
        hipLaunchKernelGGL(correct_kernel, dim3(1), dim3(64), 0, stream,
                           inputs, E, icg);
    }
    // final sweep: trajectory becomes self-consistent with corrected ICs
    hipLaunchKernelGGL(sweep_kernel, dim3(WIN), dim3(64), 0, stream,
                       inputs, lday, W1, b1, W2, b2, W3, b3, traj, icg, E);
    hipLaunchKernelGGL(out_kernel, dim3((T_TOTAL + 255) / 256), dim3(256), 0, stream,
                       inputs, traj, W1, b1, W2, b2, W3, b3, out);
}

// Round 7
// 2746.317 us; speedup vs baseline: 1.4419x; 1.4419x over previous
//
#include <hip/hip_runtime.h>
#include <math.h>

#define T_TOTAL 262144
#define HID 32
#define WIN 2048                      /* windows: 128 serial steps each */
#define WLEN (T_TOTAL / WIN)          /* 128 steps per window */
#define NSWEEP 6                      /* total sweeps; NSWEEP-1 corrections */
#define FD_EPS0 4.0                   /* FD perturbation on s0 (snow) */
#define FD_EPS1 8.0                   /* FD perturbation on s1 (water) */
#define LOG2E 1.4426950408889634f
#define TANH2C 2.8853900817779268f    /* 2*log2e */
#define NEG10LOG2E (-14.426950408889634f)
#define POS10LOG2E (14.426950408889634f)

#define PIN(x) asm volatile("" : "+v"(x))

typedef _Float16 f16x8 __attribute__((ext_vector_type(8)));
typedef float f32x4 __attribute__((ext_vector_type(4)));

__device__ __forceinline__ float fexp2(float x) { return __builtin_amdgcn_exp2f(x); }
__device__ __forceinline__ float frcp(float x)  { return __builtin_amdgcn_rcpf(x); }
__device__ __forceinline__ float fast_sig10(float x) {
    return frcp(1.0f + fexp2(x * NEG10LOG2E));
}
__device__ __forceinline__ float fast_tanh_clamp(float x) { // out_kernel only
    float xc = __builtin_amdgcn_fmed3f(x, -9.0f, 9.0f);
    float u  = fexp2(xc * TANH2C);
    return fmaf(-2.0f, frcp(u + 1.0f), 1.0f);
}
__device__ __forceinline__ float fast_tanh_nc(float x) {
    float u = fexp2(x * TANH2C);
    return fmaf(-2.0f, frcp(u + 1.0f), 1.0f);
}

// ---- DPP / lane helpers ----------------------------------------------------
template <int CTRL>
__device__ __forceinline__ float dpp_add(float v) {
    int t = __builtin_amdgcn_update_dpp(0, __float_as_int(v), CTRL, 0xF, 0xF, true);
    return v + __int_as_float(t);
}
__device__ __forceinline__ float allsum16(float x) {
    x = dpp_add<0xB1>(x);   // quad_perm xor1
    x = dpp_add<0x4E>(x);   // quad_perm xor2
    x = dpp_add<0x141>(x);  // row_half_mirror
    x = dpp_add<0x140>(x);  // row_mirror
    return x;
}
__device__ __forceinline__ int dpp_xor1_i(int v) {
    return __builtin_amdgcn_update_dpp(0, v, 0xB1, 0xF, 0xF, true);
}
__device__ __forceinline__ float rl(float x, int lane) {
    return __int_as_float(__builtin_amdgcn_readlane(__float_as_int(x), lane));
}
__device__ __forceinline__ float bpf(int addr, float x) {
    return __int_as_float(__builtin_amdgcn_ds_bpermute(addr, __float_as_int(x)));
}

// ---------------------------------------------------------------------------
// init: all window ICs = global Y0 guess
// ---------------------------------------------------------------------------
__global__ void init_kernel(const float* __restrict__ inputs, double2* icg) {
    int w = blockIdx.x * blockDim.x + threadIdx.x;
    if (w < WIN) icg[w] = make_double2((double)inputs[0], (double)inputs[1]);
}

// ---------------------------------------------------------------------------
// Newton-Parareal sweep, FOUR trajectory slots per wave (3 used):
//   quad 0 = unperturbed, quad 1 = +FD_EPS0 on s0, quads 2,3 = +FD_EPS1 on s1
//   (quad 3 duplicates quad 2 — C-rows 2,3 mod 4 read identical packed h1).
// Layer-1: every lane computes h1 for its half's primary traj (A for lanes
//   0-31, B for 32-63; states broadcast via readlane) AND for traj C.
//   Packed f16 words: traj A at even lanes 0-31, B at even lanes 32-63,
//   C at odd lanes (odd lanes' words were unused in the 2-traj scheme).
//   A-fragment row class r&3 in {0,1,2,3} gathers from {+0,+128,+4,+132}.
//   The same 4 MFMAs then serve all three trajectories (C rows 4q+0..3).
// Layer-3: each quad computes its own trajectory's 5 output channels
//   (cols 0-4) + 4 sigmoid slots (cols 5-8: s0, s1, tm_mid, tm_end);
//   per-quad ds_bpermute gathers at base 64*quad; stm recurrence reads
//   quad-0 cols 7,8 via readlane (wave-uniform forcing).
// Validated in R6: absmax at bf16 floor, sweep 333 us @ 2 waves/SIMD.
// ---------------------------------------------------------------------------
__global__ __launch_bounds__(64, 1) void sweep_kernel(
    const float* __restrict__ inputs,   // (T,5)
    const float* __restrict__ lday,     // (T,)
    const float* __restrict__ W1, const float* __restrict__ b1,
    const float* __restrict__ W2, const float* __restrict__ b2,
    const float* __restrict__ W3, const float* __restrict__ b3,
    float* __restrict__ traj,           // (T,2)
    const double2* __restrict__ icg,    // window ICs (read)
    double2* __restrict__ E)            // end states (write), 3*WIN
{
    const int lane = threadIdx.x;
    const int col  = lane & 15;
    const int quad = lane >> 4;
    const int j32  = lane & 31;
    const int half = lane >> 5;
    const bool odd = (lane & 1) != 0;

    const int wnd  = blockIdx.x;
    const int S    = wnd * WLEN;
    const int endStep = (S + WLEN < T_TOTAL - 1) ? (S + WLEN) : (T_TOTAL - 1);

    // layer-1 weights, pre-scaled by 2log2e
    float w1c0 = W1[0 * HID + j32] * TANH2C, w1c1 = W1[1 * HID + j32] * TANH2C;
    float w1c2 = W1[2 * HID + j32] * TANH2C, w1c3 = W1[3 * HID + j32] * TANH2C;
    float b1j = b1[j32] * TANH2C;
    PIN(w1c0); PIN(w1c1); PIN(w1c2); PIN(w1c3); PIN(b1j);

    // W2*2log2e as f16 hi/lo B-fragments
    f16x8 Bhi0, Blo0, Bhi1, Blo1;
#pragma unroll
    for (int jj = 0; jj < 8; ++jj) {
        float w0 = W2[(quad * 8 + jj) * HID + col] * TANH2C;
        float w1v = W2[(quad * 8 + jj) * HID + col + 16] * TANH2C;
        _Float16 h0 = (_Float16)w0, h1v = (_Float16)w1v;
        Bhi0[jj] = h0;  Blo0[jj] = (_Float16)(w0 - (float)h0);
        Bhi1[jj] = h1v; Blo1[jj] = (_Float16)(w1v - (float)h1v);
    }
    PIN(Bhi0); PIN(Blo0); PIN(Bhi1); PIN(Blo1);

    float b2a2 = b2[col] * TANH2C, b2b2 = b2[col + 16] * TANH2C;
    f32x4 cb0 = {b2a2, b2a2, b2a2, b2a2};
    f32x4 cb1 = {b2b2, b2b2, b2b2, b2b2};
    PIN(cb0); PIN(cb1);

    // layer-3 weights: 5 channels per 16-lane quad
    float wca[5], wcb[5];
#pragma unroll
    for (int c = 0; c < 5; ++c) {
        wca[c] = W3[col * 5 + c] * LOG2E;
        wcb[c] = W3[(col + 16) * 5 + c] * LOG2E;
        PIN(wca[c]); PIN(wcb[c]);
    }

    float m0 = (col == 0) ? 1.f : 0.f;
    float m1 = (col == 1) ? 1.f : 0.f;
    float m2 = (col == 2) ? 1.f : 0.f;
    float m3 = (col == 3) ? 1.f : 0.f;
    float m4 = (col == 4) ? 1.f : 0.f;
    float m5 = (col == 5) ? 1.f : 0.f;
    float m6 = (col == 6) ? 1.f : 0.f;
    float m7 = (col == 7) ? 1.f : 0.f;
    float m8 = (col == 8) ? 1.f : 0.f;
    float sig1m = (col >= 5 && col <= 8) ? 1.f : 0.f;
    float zb = b3[(col < 5) ? col : 0];
    float zconst = (col < 5) ? zb * LOG2E : 0.f;
    PIN(m0); PIN(m1); PIN(m2); PIN(m3); PIN(m4); PIN(m5); PIN(m6); PIN(m7); PIN(m8);
    PIN(sig1m); PIN(zconst);

    int psel = (lane & 1) ? 0x01000504 : 0x05040100;
    // A-build gather base by row class r&3: {A,B,C,C-dup} -> {+0,+128,+4,+132}
    int l3 = lane & 3;
    int roff = (l3 == 1) ? 128 : (l3 == 2) ? 4 : (l3 == 3) ? 132 : 0;
    int bbase = 32 * quad + roff;
    int bp0 = bbase, bp1 = bbase + 8, bp2 = bbase + 16, bp3 = bbase + 24;
    PIN(psel); PIN(bp0); PIN(bp1); PIN(bp2); PIN(bp3);

    // per-quad output-gather addresses (bytes)
    int qb = 64 * quad;
    int a_sh0 = qb + 0,  a_sh1 = qb + 4,  a_sh2 = qb + 8;
    int a_e3  = qb + 12, a_e4  = qb + 16, a_sg0 = qb + 20, a_sg1 = qb + 24;
    PIN(a_sh0); PIN(a_sh1); PIN(a_sh2); PIN(a_e3); PIN(a_e4); PIN(a_sg0); PIN(a_sg1);

    double2 ic = icg[wnd];
    double y0 = ic.x + ((quad == 1) ? FD_EPS0 : 0.0);
    double y1 = ic.y + ((quad >= 2) ? FD_EPS1 : 0.0);
    float2* traj2 = (float2*)traj;
    if (lane == 0 && wnd == 0)
        traj2[0] = make_float2((float)ic.x, (float)ic.y);

    auto rhs = [&](float s0q, float s1q, float base, float stm, float ld, float zoffk,
                   float& d0, float& d1, float& rout) {
        // broadcast the three trajectory states for layer-1
        float s0A = rl(s0q, 0),  s1A = rl(s1q, 0);
        float s0B = rl(s0q, 16), s1B = rl(s1q, 16);
        float s0C = rl(s0q, 32), s1C = rl(s1q, 32);
        float s0p = half ? s0B : s0A;
        float s1p = half ? s1B : s1A;
        // layer-1: primary (A/B by half) and C (all lanes)
        float prep = fmaf(s1p, w1c1, fmaf(s0p, w1c0, base));
        float prec = fmaf(s1C, w1c1, fmaf(s0C, w1c0, base));
        float up_ = fexp2(prep);
        float uc_ = fexp2(prec);
        float h1p = fmaf(-2.0f, frcp(up_ + 1.0f), 1.0f);
        float h1c = fmaf(-2.0f, frcp(uc_ + 1.0f), 1.0f);
        union { _Float16 h; unsigned short u; } cvp, cvc;
        cvp.h = (_Float16)h1p; cvc.h = (_Float16)h1c;
        int ownp = (int)cvp.u, ownc = (int)cvc.u;
        int nbp = dpp_xor1_i(ownp), nbc = dpp_xor1_i(ownc);
        int pkp = __builtin_amdgcn_perm(nbp, ownp, psel);
        int pkc = __builtin_amdgcn_perm(nbc, ownc, psel);
        int pk  = odd ? pkc : pkp;
        int g0i = __builtin_amdgcn_ds_bpermute(bp0, pk);
        int g1i = __builtin_amdgcn_ds_bpermute(bp1, pk);
        int g2i = __builtin_amdgcn_ds_bpermute(bp2, pk);
        int g3i = __builtin_amdgcn_ds_bpermute(bp3, pk);
        union { int i[4]; f16x8 h; } au;
        au.i[0] = g0i; au.i[1] = g1i; au.i[2] = g2i; au.i[3] = g3i;
        f16x8 A = au.h;
        f32x4 zz = {0.f, 0.f, 0.f, 0.f};
        f32x4 chi0 = __builtin_amdgcn_mfma_f32_16x16x32_f16(A, Bhi0, cb0, 0, 0, 0);
        f32x4 clo0 = __builtin_amdgcn_mfma_f32_16x16x32_f16(A, Blo0, zz, 0, 0, 0);
        f32x4 chi1 = __builtin_amdgcn_mfma_f32_16x16x32_f16(A, Bhi1, cb1, 0, 0, 0);
        f32x4 clo1 = __builtin_amdgcn_mfma_f32_16x16x32_f16(A, Blo1, zz, 0, 0, 0);
        // per-quad trajectory row select (C rows: 4q+0=A, +1=B, +2=C, +3=C-dup)
        float tA0 = chi0[0] + clo0[0], tB0 = chi0[1] + clo0[1], tC0 = chi0[2] + clo0[2];
        float tA1 = chi1[0] + clo1[0], tB1 = chi1[1] + clo1[1], tC1 = chi1[2] + clo1[2];
        float t0 = (quad == 1) ? tB0 : (quad >= 2) ? tC0 : tA0;
        float t1 = (quad == 1) ? tB1 : (quad >= 2) ? tC1 : tA1;
        float ua = fexp2(t0);
        float ub = fexp2(t1);
        float g0 = fmaf(-2.0f, frcp(ua + 1.0f), 1.0f);
        float g1 = fmaf(-2.0f, frcp(ub + 1.0f), 1.0f);
        float r0 = fmaf(g0, wca[0], g1 * wcb[0]);
        float r1 = fmaf(g0, wca[1], g1 * wcb[1]);
        float r2 = fmaf(g0, wca[2], g1 * wcb[2]);
        float r3 = fmaf(g0, wca[3], g1 * wcb[3]);
        float r4 = fmaf(g0, wca[4], g1 * wcb[4]);
        float s0r = allsum16(r0);
        float s1r = allsum16(r1);
        float s2r = allsum16(r2);
        float s3r = allsum16(r3);
        float s4r = allsum16(r4);
        float zs0 = s0q * NEG10LOG2E;           // own quad's trajectory
        float zs1 = s1q * NEG10LOG2E;
        float zoff = fmaf(zs0, m5, fmaf(zs1, m6, zoffk));
        float zarg = fmaf(s0r, m0, fmaf(s1r, m1, fmaf(s2r, m2,
                     fmaf(s3r, m3, fmaf(s4r, m4, zoff)))));
        float u = fexp2(zarg);
        float r = frcp(u + sig1m);
        float w = fmaf(0.5f, u, -0.5f * r);
        float sh0 = bpf(a_sh0, w), sh1 = bpf(a_sh1, w), sh2 = bpf(a_sh2, w);
        float e3  = bpf(a_e3, u),  e4  = bpf(a_e4, u);
        float sg0 = bpf(a_sg0, r), sg1 = bpf(a_sg1, r);
        float p_snow = fmaxf(sh0 * stm, 0.f);
        float p_rain = fmaxf(sh1, 0.f);
        float melt   = fmaxf(sg0 * sh2, 0.f);
        float etq    = sg1 * fmaf(e3, ld, e4);
        d0 = p_snow - melt;
        d1 = (p_rain + melt) - etq;
        rout = r;
    };

    float pA = inputs[S * 5 + 2],       tmA = inputs[S * 5 + 3],       ldA = lday[S];
    float pB = inputs[(S + 1) * 5 + 2], tmB = inputs[(S + 1) * 5 + 3], ldB = lday[S + 1];
    float pC = inputs[(S + 2) * 5 + 2], tmC = inputs[(S + 2) * 5 + 3], ldC = lday[S + 2];
    float stmA = fast_sig10(-tmA);
    float stmB = fast_sig10(-tmB);
    float stmm = fast_sig10(-0.5f * (tmA + tmB));
    float baseA = fmaf(pA, w1c2, fmaf(tmA, w1c3, b1j));
    float baseB = fmaf(pB, w1c2, fmaf(tmB, w1c3, b1j));

    for (int n = S; n < endStep; ++n) {
        const float ldm = 0.5f * (ldA + ldB);
        const float pm  = 0.5f * (pA + pB);
        const float tmm = 0.5f * (tmA + tmB);
        const float basem = fmaf(pm, w1c2, fmaf(tmm, w1c3, b1j));
        const float ztm_m = (0.5f * (tmB + tmC)) * POS10LOG2E;
        const float ztm_b = tmC * POS10LOG2E;
        const float zoffk = fmaf(ztm_m, m7, fmaf(ztm_b, m8, zconst));

        const float fy0 = (float)y0, fy1 = (float)y1;
        float k10, k11, k20, k21, k30, k31, k40, k41, rd;
        rhs(fy0,                  fy1,                  baseA, stmA, ldA, zoffk, k10, k11, rd);
        rhs(fmaf(0.5f, k10, fy0), fmaf(0.5f, k11, fy1), basem, stmm, ldm, zoffk, k20, k21, rd);
        rhs(fmaf(0.5f, k20, fy0), fmaf(0.5f, k21, fy1), basem, stmm, ldm, zoffk, k30, k31, rd);
        rhs(fy0 + k30,            fy1 + k31,            baseB, stmB, ldB, zoffk, k40, k41, rd);
        const float stmm_n = rl(rd, 7);
        const float stmB_n = rl(rd, 8);

        const float s0sum = (k10 + 2.0f * k20) + (2.0f * k30 + k40);
        const float s1sum = (k11 + 2.0f * k21) + (2.0f * k31 + k41);
        y0 += (1.0 / 6.0) * (double)s0sum;
        y1 += (1.0 / 6.0) * (double)s1sum;

        if (lane == 0)
            traj2[n + 1] = make_float2((float)y0, (float)y1);

        stmA = stmB; stmB = stmB_n; stmm = stmm_n;
        baseA = baseB;
        baseB = fmaf(pC, w1c2, fmaf(tmC, w1c3, b1j));
        pA = pB; tmA = tmB; ldA = ldB;
        pB = pC; tmB = tmC; ldB = ldC;
        const int np3 = (n + 3 < T_TOTAL) ? (n + 3) : (T_TOTAL - 1);
        pC = inputs[np3 * 5 + 2]; tmC = inputs[np3 * 5 + 3]; ldC = lday[np3];
    }

    if (lane == 0)  E[wnd]           = make_double2(y0, y1);  // unperturbed
    if (lane == 16) E[WIN + wnd]     = make_double2(y0, y1);  // +eps0 on s0
    if (lane == 32) E[2 * WIN + wnd] = make_double2(y0, y1);  // +eps1 on s1
}

// ---------------------------------------------------------------------------
// Sequential Newton-Parareal correction, restructured (R6 post-mortem: the
// serial loop cost ~170 us because FD division, clamping, and LDS reads sat
// inside the dependent f64 chain with exposed LDS latency).
// Phase 1 (all 64 lanes): compute CLAMPED float J and staging arrays in LDS.
// Phase 2 (lane 0): pure affine recurrence, ~6 dependent f64 ops per window,
// with 1-ahead register prefetch of LDS operands so load latency hides.
// Clamps wide-open for WLEN=128 (R6-validated).  J01 := 0.
// ---------------------------------------------------------------------------
__global__ __launch_bounds__(64) void correct_kernel(
    const float* __restrict__ inputs,
    const double2* __restrict__ E,
    double2* __restrict__ icg) {
    __shared__ float sJ00[WIN], sJ10[WIN], sJ11[WIN];
    __shared__ float sE0x[WIN], sE0y[WIN];
    __shared__ float sGx[WIN], sGy[WIN];
    for (int i = threadIdx.x; i < WIN; i += 64) {
        double2 e0 = E[i];
        double2 e1 = E[WIN + i];
        double2 e2 = E[2 * WIN + i];
        double2 g  = icg[i];
        float J00 = (float)((e1.x - e0.x) * (1.0 / FD_EPS0));
        float J10 = (float)((e1.y - e0.y) * (1.0 / FD_EPS0));
        float J11 = (float)((e2.y - e0.y) * (1.0 / FD_EPS1));
        sJ00[i] = fminf(fmaxf(J00, -0.15f), 1.15f);   // wide-open (R6)
        sJ10[i] = fminf(fmaxf(J10, -0.30f), 1.80f);
        sJ11[i] = fminf(fmaxf(J11,  0.00f), 1.10f);
        sE0x[i] = (float)e0.x; sE0y[i] = (float)e0.y;
        sGx[i]  = (float)g.x;  sGy[i]  = (float)g.y;
    }
    __syncthreads();
    if (threadIdx.x != 0) return;

    double y0c = (double)inputs[0];
    double y1c = (double)inputs[1];
    // prefetch window 0
    float j00 = sJ00[0], j10 = sJ10[0], j11 = sJ11[0];
    float e0x = sE0x[0], e0y = sE0y[0];
    float gx  = sGx[0],  gy  = sGy[0];
    for (int w = 0; w < WIN; ++w) {
        // prefetch next window's operands (independent of the f64 chain)
        int wn = (w + 1 < WIN) ? (w + 1) : w;
        float nj00 = sJ00[wn], nj10 = sJ10[wn], nj11 = sJ11[wn];
        float ne0x = sE0x[wn], ne0y = sE0y[wn];
        float ngx  = sGx[wn],  ngy  = sGy[wn];

        double d0 = y0c - (double)gx;
        double d1 = y1c - (double)gy;
        d0 = fmin(fmax(d0, -50.0), 50.0);      // trust region
        d1 = fmin(fmax(d1, -400.0), 400.0);
        icg[w] = make_double2(y0c, y1c);       // fire-and-forget store
        y0c = (double)e0x + (double)j00 * d0;  // J01 = 0
        y1c = (double)e0y + (double)j10 * d0 + (double)j11 * d1;
        y0c = fmin(fmax(y0c, -5.0), 1000.0);   // physical sanity
        y1c = fmin(fmax(y1c, -5.0), 5000.0);

        j00 = nj00; j10 = nj10; j11 = nj11;
        e0x = ne0x; e0y = ne0y; gx = ngx; gy = ngy;
    }
}

// ---------------------------------------------------------------------------
// Parallel readout: out[t] = mlp(relu(state), p, tm)[4]
// ---------------------------------------------------------------------------
__global__ __launch_bounds__(256) void out_kernel(
    const float* __restrict__ inputs,
    const float* __restrict__ traj,
    const float* __restrict__ W1, const float* __restrict__ b1,
    const float* __restrict__ W2, const float* __restrict__ b2,
    const float* __restrict__ W3, const float* __restrict__ b3,
    float* __restrict__ out)
{
    __shared__ float sW1[4 * HID];
    __shared__ float sb1[HID];
    __shared__ float sW2T[HID * HID];
    __shared__ float sb2[HID];
    __shared__ float sw3[HID];
    for (int i = threadIdx.x; i < 4 * HID; i += 256) sW1[i] = W1[i];
    for (int i = threadIdx.x; i < HID; i += 256) {
        sb1[i] = b1[i]; sb2[i] = b2[i]; sw3[i] = W3[i * 5 + 4];
    }
    for (int idx = threadIdx.x; idx < HID * HID; idx += 256) {
        int jj = idx >> 5, ii = idx & 31;
        sW2T[idx] = W2[ii * HID + jj];
    }
    __syncthreads();

    int t = blockIdx.x * 256 + threadIdx.x;
    if (t >= T_TOTAL) return;

    float2 st = ((const float2*)traj)[t];
    float s0 = fmaxf(st.x, 0.0f);
    float s1 = fmaxf(st.y, 0.0f);
    float p  = inputs[t * 5 + 2];
    float tm = inputs[t * 5 + 3];

    float h1[HID];
#pragma unroll
    for (int jj = 0; jj < HID; ++jj) {
        float pre = fmaf(s0, sW1[jj], fmaf(s1, sW1[HID + jj],
                    fmaf(p, sW1[2 * HID + jj],
                    fmaf(tm, sW1[3 * HID + jj], sb1[jj]))));
        h1[jj] = fast_tanh_clamp(pre);
    }
    float o = b3[4];
#pragma unroll 4
    for (int jj = 0; jj < HID; ++jj) {
        float a0 = sb2[jj], a1 = 0.f, a2 = 0.f, a3 = 0.f;
#pragma unroll
        for (int ii = 0; ii < HID; ii += 4) {
            a0 = fmaf(h1[ii + 0], sW2T[jj * HID + ii + 0], a0);
            a1 = fmaf(h1[ii + 1], sW2T[jj * HID + ii + 1], a1);
            a2 = fmaf(h1[ii + 2], sW2T[jj * HID + ii + 2], a2);
            a3 = fmaf(h1[ii + 3], sW2T[jj * HID + ii + 3], a3);
        }
        o = fmaf(fast_tanh_nc((a0 + a1) + (a2 + a3)), sw3[jj], o);
    }
    out[t] = o;
}

extern "C" void kernel_launch(void* const* d_in, const int* in_sizes, int n_in,
                              void* d_out, int out_size, void* d_ws, size_t ws_size,
                              hipStream_t stream) {
    (void)in_sizes; (void)n_in; (void)out_size; (void)ws_size;
    const float* inputs = (const float*)d_in[0];
    const float* lday   = (const float*)d_in[1];
    const float* W1     = (const float*)d_in[2];
    const float* b1     = (const float*)d_in[3];
    const float* W2     = (const float*)d_in[4];
    const float* b2     = (const float*)d_in[5];
    const float* W3     = (const float*)d_in[6];
    const float* b3     = (const float*)d_in[7];
    float* out  = (float*)d_out;
    float* traj = (float*)d_ws;                 // T*2 floats = 2 MB

    // small Parareal arrays live in d_out (scratch until out_kernel)
    // E = 3*WIN double2 = 96 KB at offset 0; icg = WIN double2 = 32 KB at +128 KB
    char* scr = (char*)d_out;
    double2* E   = (double2*)scr;
    double2* icg = (double2*)(scr + 131072);

    hipLaunchKernelGGL(init_kernel, dim3((WIN + 255) / 256), dim3(256), 0, stream,
                       inputs, icg);
    for (int k = 0; k < NSWEEP - 1; ++k) {
        hipLaunchKernelGGL(sweep_kernel, dim3(WIN), dim3(64), 0, stream,
                           inputs, lday, W1, b1, W2, b2, W3, b3, traj, icg, E);
        hipLaunchKernelGGL(correct_kernel, dim3(1), dim3(64), 0, stream,
                           inputs, E, icg);
    }
    // final sweep: trajectory becomes self-consistent with corrected ICs
    hipLaunchKernelGGL(sweep_kernel, dim3(WIN), dim3(64), 0, stream,
                       inputs, lday, W1, b1, W2, b2, W3, b3, traj, icg, E);
    hipLaunchKernelGGL(out_kernel, dim3((T_TOTAL + 255) / 256), dim3(256), 0, stream,
                       inputs, traj, W1, b1, W2, b2, W3, b3, out);
}

// Round 8
// 2207.814 us; speedup vs baseline: 1.7936x; 1.2439x over previous
//
#include <hip/hip_runtime.h>
#include <math.h>

#define T_TOTAL 262144
#define HID 32
#define WIN 2048                      /* windows: 128 serial steps each */
#define WLEN (T_TOTAL / WIN)          /* 128 steps per window */
#define NSWEEP 6                      /* total sweeps; NSWEEP-1 corrections */
#define FD_EPS0 4.0                   /* FD perturbation on s0 (snow) */
#define FD_EPS1 8.0                   /* FD perturbation on s1 (water) */
#define LOG2E 1.4426950408889634f
#define TANH2C 2.8853900817779268f    /* 2*log2e */
#define NEG10LOG2E (-14.426950408889634f)
#define POS10LOG2E (14.426950408889634f)

#define PIN(x) asm volatile("" : "+v"(x))

typedef _Float16 f16x8 __attribute__((ext_vector_type(8)));
typedef float f32x4 __attribute__((ext_vector_type(4)));

__device__ __forceinline__ float fexp2(float x) { return __builtin_amdgcn_exp2f(x); }
__device__ __forceinline__ float frcp(float x)  { return __builtin_amdgcn_rcpf(x); }
__device__ __forceinline__ float fast_sig10(float x) {
    return frcp(1.0f + fexp2(x * NEG10LOG2E));
}
__device__ __forceinline__ float fast_tanh_clamp(float x) { // out_kernel only
    float xc = __builtin_amdgcn_fmed3f(x, -9.0f, 9.0f);
    float u  = fexp2(xc * TANH2C);
    return fmaf(-2.0f, frcp(u + 1.0f), 1.0f);
}
__device__ __forceinline__ float fast_tanh_nc(float x) {
    float u = fexp2(x * TANH2C);
    return fmaf(-2.0f, frcp(u + 1.0f), 1.0f);
}

// ---- DPP / lane helpers ----------------------------------------------------
template <int CTRL>
__device__ __forceinline__ float dpp_add(float v) {
    int t = __builtin_amdgcn_update_dpp(0, __float_as_int(v), CTRL, 0xF, 0xF, true);
    return v + __int_as_float(t);
}
__device__ __forceinline__ float allsum16(float x) {
    x = dpp_add<0xB1>(x);   // quad_perm xor1
    x = dpp_add<0x4E>(x);   // quad_perm xor2
    x = dpp_add<0x141>(x);  // row_half_mirror
    x = dpp_add<0x140>(x);  // row_mirror
    return x;
}
__device__ __forceinline__ int dpp_xor1_i(int v) {
    return __builtin_amdgcn_update_dpp(0, v, 0xB1, 0xF, 0xF, true);
}
__device__ __forceinline__ float rl(float x, int lane) {
    return __int_as_float(__builtin_amdgcn_readlane(__float_as_int(x), lane));
}
__device__ __forceinline__ float bpf(int addr, float x) {
    return __int_as_float(__builtin_amdgcn_ds_bpermute(addr, __float_as_int(x)));
}

// ---------------------------------------------------------------------------
// init: all window ICs = global Y0 guess (f32 — correction runs in f32; the
// ~1e-4 IC rounding is invisible under the bf16 output floor)
// ---------------------------------------------------------------------------
__global__ void init_kernel(const float* __restrict__ inputs, float2* icg) {
    int w = blockIdx.x * blockDim.x + threadIdx.x;
    if (w < WIN) icg[w] = make_float2(inputs[0], inputs[1]);
}

// ---------------------------------------------------------------------------
// Newton-Parareal sweep, FOUR trajectory slots per wave (3 used):
//   quad 0 = unperturbed, quad 1 = +FD_EPS0 on s0, quads 2,3 = +FD_EPS1 on s1
//   (quad 3 duplicates quad 2 — C-rows 2,3 mod 4 read identical packed h1).
// Layer-1: every lane computes h1 for its half's primary traj (A for lanes
//   0-31, B for 32-63; states broadcast via readlane) AND for traj C.
//   A-fragment row class r&3 in {0,1,2,3} gathers from {+0,+128,+4,+132}.
//   The same 4 MFMAs then serve all three trajectories (C rows 4q+0..3).
// Layer-3: each quad computes its own trajectory's 5 output channels
//   (cols 0-4) + 4 sigmoid slots (cols 5-8); per-quad ds_bpermute gathers.
// Validated R6/R7: absmax at bf16 floor, sweep ~334 us @ 2 waves/SIMD.
// Internal integration stays f64; only the IC read is f32 now.
// ---------------------------------------------------------------------------
__global__ __launch_bounds__(64, 1) void sweep_kernel(
    const float* __restrict__ inputs,   // (T,5)
    const float* __restrict__ lday,     // (T,)
    const float* __restrict__ W1, const float* __restrict__ b1,
    const float* __restrict__ W2, const float* __restrict__ b2,
    const float* __restrict__ W3, const float* __restrict__ b3,
    float* __restrict__ traj,           // (T,2)
    const float2* __restrict__ icg,     // window ICs (read, f32)
    double2* __restrict__ E)            // end states (write), 3*WIN
{
    const int lane = threadIdx.x;
    const int col  = lane & 15;
    const int quad = lane >> 4;
    const int j32  = lane & 31;
    const int half = lane >> 5;
    const bool odd = (lane & 1) != 0;

    const int wnd  = blockIdx.x;
    const int S    = wnd * WLEN;
    const int endStep = (S + WLEN < T_TOTAL - 1) ? (S + WLEN) : (T_TOTAL - 1);

    // layer-1 weights, pre-scaled by 2log2e
    float w1c0 = W1[0 * HID + j32] * TANH2C, w1c1 = W1[1 * HID + j32] * TANH2C;
    float w1c2 = W1[2 * HID + j32] * TANH2C, w1c3 = W1[3 * HID + j32] * TANH2C;
    float b1j = b1[j32] * TANH2C;
    PIN(w1c0); PIN(w1c1); PIN(w1c2); PIN(w1c3); PIN(b1j);

    // W2*2log2e as f16 hi/lo B-fragments
    f16x8 Bhi0, Blo0, Bhi1, Blo1;
#pragma unroll
    for (int jj = 0; jj < 8; ++jj) {
        float w0 = W2[(quad * 8 + jj) * HID + col] * TANH2C;
        float w1v = W2[(quad * 8 + jj) * HID + col + 16] * TANH2C;
        _Float16 h0 = (_Float16)w0, h1v = (_Float16)w1v;
        Bhi0[jj] = h0;  Blo0[jj] = (_Float16)(w0 - (float)h0);
        Bhi1[jj] = h1v; Blo1[jj] = (_Float16)(w1v - (float)h1v);
    }
    PIN(Bhi0); PIN(Blo0); PIN(Bhi1); PIN(Blo1);

    float b2a2 = b2[col] * TANH2C, b2b2 = b2[col + 16] * TANH2C;
    f32x4 cb0 = {b2a2, b2a2, b2a2, b2a2};
    f32x4 cb1 = {b2b2, b2b2, b2b2, b2b2};
    PIN(cb0); PIN(cb1);

    // layer-3 weights: 5 channels per 16-lane quad
    float wca[5], wcb[5];
#pragma unroll
    for (int c = 0; c < 5; ++c) {
        wca[c] = W3[col * 5 + c] * LOG2E;
        wcb[c] = W3[(col + 16) * 5 + c] * LOG2E;
        PIN(wca[c]); PIN(wcb[c]);
    }

    float m0 = (col == 0) ? 1.f : 0.f;
    float m1 = (col == 1) ? 1.f : 0.f;
    float m2 = (col == 2) ? 1.f : 0.f;
    float m3 = (col == 3) ? 1.f : 0.f;
    float m4 = (col == 4) ? 1.f : 0.f;
    float m5 = (col == 5) ? 1.f : 0.f;
    float m6 = (col == 6) ? 1.f : 0.f;
    float m7 = (col == 7) ? 1.f : 0.f;
    float m8 = (col == 8) ? 1.f : 0.f;
    float sig1m = (col >= 5 && col <= 8) ? 1.f : 0.f;
    float zb = b3[(col < 5) ? col : 0];
    float zconst = (col < 5) ? zb * LOG2E : 0.f;
    PIN(m0); PIN(m1); PIN(m2); PIN(m3); PIN(m4); PIN(m5); PIN(m6); PIN(m7); PIN(m8);
    PIN(sig1m); PIN(zconst);

    int psel = (lane & 1) ? 0x01000504 : 0x05040100;
    // A-build gather base by row class r&3: {A,B,C,C-dup} -> {+0,+128,+4,+132}
    int l3 = lane & 3;
    int roff = (l3 == 1) ? 128 : (l3 == 2) ? 4 : (l3 == 3) ? 132 : 0;
    int bbase = 32 * quad + roff;
    int bp0 = bbase, bp1 = bbase + 8, bp2 = bbase + 16, bp3 = bbase + 24;
    PIN(psel); PIN(bp0); PIN(bp1); PIN(bp2); PIN(bp3);

    // per-quad output-gather addresses (bytes)
    int qb = 64 * quad;
    int a_sh0 = qb + 0,  a_sh1 = qb + 4,  a_sh2 = qb + 8;
    int a_e3  = qb + 12, a_e4  = qb + 16, a_sg0 = qb + 20, a_sg1 = qb + 24;
    PIN(a_sh0); PIN(a_sh1); PIN(a_sh2); PIN(a_e3); PIN(a_e4); PIN(a_sg0); PIN(a_sg1);

    float2 ic = icg[wnd];
    double y0 = (double)ic.x + ((quad == 1) ? FD_EPS0 : 0.0);
    double y1 = (double)ic.y + ((quad >= 2) ? FD_EPS1 : 0.0);
    float2* traj2 = (float2*)traj;
    if (lane == 0 && wnd == 0)
        traj2[0] = make_float2(ic.x, ic.y);

    auto rhs = [&](float s0q, float s1q, float base, float stm, float ld, float zoffk,
                   float& d0, float& d1, float& rout) {
        // broadcast the three trajectory states for layer-1
        float s0A = rl(s0q, 0),  s1A = rl(s1q, 0);
        float s0B = rl(s0q, 16), s1B = rl(s1q, 16);
        float s0C = rl(s0q, 32), s1C = rl(s1q, 32);
        float s0p = half ? s0B : s0A;
        float s1p = half ? s1B : s1A;
        // layer-1: primary (A/B by half) and C (all lanes)
        float prep = fmaf(s1p, w1c1, fmaf(s0p, w1c0, base));
        float prec = fmaf(s1C, w1c1, fmaf(s0C, w1c0, base));
        float up_ = fexp2(prep);
        float uc_ = fexp2(prec);
        float h1p = fmaf(-2.0f, frcp(up_ + 1.0f), 1.0f);
        float h1c = fmaf(-2.0f, frcp(uc_ + 1.0f), 1.0f);
        union { _Float16 h; unsigned short u; } cvp, cvc;
        cvp.h = (_Float16)h1p; cvc.h = (_Float16)h1c;
        int ownp = (int)cvp.u, ownc = (int)cvc.u;
        int nbp = dpp_xor1_i(ownp), nbc = dpp_xor1_i(ownc);
        int pkp = __builtin_amdgcn_perm(nbp, ownp, psel);
        int pkc = __builtin_amdgcn_perm(nbc, ownc, psel);
        int pk  = odd ? pkc : pkp;
        int g0i = __builtin_amdgcn_ds_bpermute(bp0, pk);
        int g1i = __builtin_amdgcn_ds_bpermute(bp1, pk);
        int g2i = __builtin_amdgcn_ds_bpermute(bp2, pk);
        int g3i = __builtin_amdgcn_ds_bpermute(bp3, pk);
        union { int i[4]; f16x8 h; } au;
        au.i[0] = g0i; au.i[1] = g1i; au.i[2] = g2i; au.i[3] = g3i;
        f16x8 A = au.h;
        f32x4 zz = {0.f, 0.f, 0.f, 0.f};
        f32x4 chi0 = __builtin_amdgcn_mfma_f32_16x16x32_f16(A, Bhi0, cb0, 0, 0, 0);
        f32x4 clo0 = __builtin_amdgcn_mfma_f32_16x16x32_f16(A, Blo0, zz, 0, 0, 0);
        f32x4 chi1 = __builtin_amdgcn_mfma_f32_16x16x32_f16(A, Bhi1, cb1, 0, 0, 0);
        f32x4 clo1 = __builtin_amdgcn_mfma_f32_16x16x32_f16(A, Blo1, zz, 0, 0, 0);
        // per-quad trajectory row select (C rows: 4q+0=A, +1=B, +2=C, +3=C-dup)
        float tA0 = chi0[0] + clo0[0], tB0 = chi0[1] + clo0[1], tC0 = chi0[2] + clo0[2];
        float tA1 = chi1[0] + clo1[0], tB1 = chi1[1] + clo1[1], tC1 = chi1[2] + clo1[2];
        float t0 = (quad == 1) ? tB0 : (quad >= 2) ? tC0 : tA0;
        float t1 = (quad == 1) ? tB1 : (quad >= 2) ? tC1 : tA1;
        float ua = fexp2(t0);
        float ub = fexp2(t1);
        float g0 = fmaf(-2.0f, frcp(ua + 1.0f), 1.0f);
        float g1 = fmaf(-2.0f, frcp(ub + 1.0f), 1.0f);
        float r0 = fmaf(g0, wca[0], g1 * wcb[0]);
        float r1 = fmaf(g0, wca[1], g1 * wcb[1]);
        float r2 = fmaf(g0, wca[2], g1 * wcb[2]);
        float r3 = fmaf(g0, wca[3], g1 * wcb[3]);
        float r4 = fmaf(g0, wca[4], g1 * wcb[4]);
        float s0r = allsum16(r0);
        float s1r = allsum16(r1);
        float s2r = allsum16(r2);
        float s3r = allsum16(r3);
        float s4r = allsum16(r4);
        float zs0 = s0q * NEG10LOG2E;           // own quad's trajectory
        float zs1 = s1q * NEG10LOG2E;
        float zoff = fmaf(zs0, m5, fmaf(zs1, m6, zoffk));
        float zarg = fmaf(s0r, m0, fmaf(s1r, m1, fmaf(s2r, m2,
                     fmaf(s3r, m3, fmaf(s4r, m4, zoff)))));
        float u = fexp2(zarg);
        float r = frcp(u + sig1m);
        float w = fmaf(0.5f, u, -0.5f * r);
        float sh0 = bpf(a_sh0, w), sh1 = bpf(a_sh1, w), sh2 = bpf(a_sh2, w);
        float e3  = bpf(a_e3, u),  e4  = bpf(a_e4, u);
        float sg0 = bpf(a_sg0, r), sg1 = bpf(a_sg1, r);
        float p_snow = fmaxf(sh0 * stm, 0.f);
        float p_rain = fmaxf(sh1, 0.f);
        float melt   = fmaxf(sg0 * sh2, 0.f);
        float etq    = sg1 * fmaf(e3, ld, e4);
        d0 = p_snow - melt;
        d1 = (p_rain + melt) - etq;
        rout = r;
    };

    float pA = inputs[S * 5 + 2],       tmA = inputs[S * 5 + 3],       ldA = lday[S];
    float pB = inputs[(S + 1) * 5 + 2], tmB = inputs[(S + 1) * 5 + 3], ldB = lday[S + 1];
    float pC = inputs[(S + 2) * 5 + 2], tmC = inputs[(S + 2) * 5 + 3], ldC = lday[S + 2];
    float stmA = fast_sig10(-tmA);
    float stmB = fast_sig10(-tmB);
    float stmm = fast_sig10(-0.5f * (tmA + tmB));
    float baseA = fmaf(pA, w1c2, fmaf(tmA, w1c3, b1j));
    float baseB = fmaf(pB, w1c2, fmaf(tmB, w1c3, b1j));

    for (int n = S; n < endStep; ++n) {
        const float ldm = 0.5f * (ldA + ldB);
        const float pm  = 0.5f * (pA + pB);
        const float tmm = 0.5f * (tmA + tmB);
        const float basem = fmaf(pm, w1c2, fmaf(tmm, w1c3, b1j));
        const float ztm_m = (0.5f * (tmB + tmC)) * POS10LOG2E;
        const float ztm_b = tmC * POS10LOG2E;
        const float zoffk = fmaf(ztm_m, m7, fmaf(ztm_b, m8, zconst));

        const float fy0 = (float)y0, fy1 = (float)y1;
        float k10, k11, k20, k21, k30, k31, k40, k41, rd;
        rhs(fy0,                  fy1,                  baseA, stmA, ldA, zoffk, k10, k11, rd);
        rhs(fmaf(0.5f, k10, fy0), fmaf(0.5f, k11, fy1), basem, stmm, ldm, zoffk, k20, k21, rd);
        rhs(fmaf(0.5f, k20, fy0), fmaf(0.5f, k21, fy1), basem, stmm, ldm, zoffk, k30, k31, rd);
        rhs(fy0 + k30,            fy1 + k31,            baseB, stmB, ldB, zoffk, k40, k41, rd);
        const float stmm_n = rl(rd, 7);
        const float stmB_n = rl(rd, 8);

        const float s0sum = (k10 + 2.0f * k20) + (2.0f * k30 + k40);
        const float s1sum = (k11 + 2.0f * k21) + (2.0f * k31 + k41);
        y0 += (1.0 / 6.0) * (double)s0sum;
        y1 += (1.0 / 6.0) * (double)s1sum;

        if (lane == 0)
            traj2[n + 1] = make_float2((float)y0, (float)y1);

        stmA = stmB; stmB = stmB_n; stmm = stmm_n;
        baseA = baseB;
        baseB = fmaf(pC, w1c2, fmaf(tmC, w1c3, b1j));
        pA = pB; tmA = tmB; ldA = ldB;
        pB = pC; tmB = tmC; ldB = ldC;
        const int np3 = (n + 3 < T_TOTAL) ? (n + 3) : (T_TOTAL - 1);
        pC = inputs[np3 * 5 + 2]; tmC = inputs[np3 * 5 + 3]; ldC = lday[np3];
    }

    if (lane == 0)  E[wnd]           = make_double2(y0, y1);  // unperturbed
    if (lane == 16) E[WIN + wnd]     = make_double2(y0, y1);  // +eps0 on s0
    if (lane == 32) E[2 * WIN + wnd] = make_double2(y0, y1);  // +eps1 on s1
}

// ---------------------------------------------------------------------------
// Sequential Newton-Parareal correction, f32 recurrence (R7 post-mortem: the
// serial loop was f64-LATENCY-bound, ~130 us — 8 dependent f64 ops x ~12 cyc
// x 2048 windows). J is still differenced in f64 during the parallel staging
// phase (preserves FD precision), then clamped to f32. The serial chain is
// now sub -> med3 -> fmaf -> med3 in f32 (~30 cyc/window). IC f32 rounding
// (~1e-4) is invisible under the bf16 output floor.
// Clamps wide-open for WLEN=128 (R6-validated). J01 := 0.
// ---------------------------------------------------------------------------
__global__ __launch_bounds__(64) void correct_kernel(
    const float* __restrict__ inputs,
    const double2* __restrict__ E,
    float2* __restrict__ icg) {
    __shared__ float sJ00[WIN], sJ10[WIN], sJ11[WIN];
    __shared__ float sE0x[WIN], sE0y[WIN];
    __shared__ float sGx[WIN], sGy[WIN];
    for (int i = threadIdx.x; i < WIN; i += 64) {
        double2 e0 = E[i];
        double2 e1 = E[WIN + i];
        double2 e2 = E[2 * WIN + i];
        float2 g   = icg[i];
        float J00 = (float)((e1.x - e0.x) * (1.0 / FD_EPS0));
        float J10 = (float)((e1.y - e0.y) * (1.0 / FD_EPS0));
        float J11 = (float)((e2.y - e0.y) * (1.0 / FD_EPS1));
        sJ00[i] = fminf(fmaxf(J00, -0.15f), 1.15f);   // wide-open (R6)
        sJ10[i] = fminf(fmaxf(J10, -0.30f), 1.80f);
        sJ11[i] = fminf(fmaxf(J11,  0.00f), 1.10f);
        sE0x[i] = (float)e0.x; sE0y[i] = (float)e0.y;
        sGx[i]  = g.x;         sGy[i]  = g.y;
    }
    __syncthreads();
    if (threadIdx.x != 0) return;

    float y0c = inputs[0];
    float y1c = inputs[1];
#pragma unroll 8
    for (int w = 0; w < WIN; ++w) {
        float d0 = y0c - sGx[w];
        float d1 = y1c - sGy[w];
        d0 = fminf(fmaxf(d0, -50.0f), 50.0f);      // trust region (med3)
        d1 = fminf(fmaxf(d1, -400.0f), 400.0f);
        icg[w] = make_float2(y0c, y1c);            // fire-and-forget store
        y0c = fmaf(sJ00[w], d0, sE0x[w]);          // J01 = 0
        y1c = fmaf(sJ10[w], d0, fmaf(sJ11[w], d1, sE0y[w]));
        y0c = fminf(fmaxf(y0c, -5.0f), 1000.0f);   // physical sanity (med3)
        y1c = fminf(fmaxf(y1c, -5.0f), 5000.0f);
    }
}

// ---------------------------------------------------------------------------
// Parallel readout: out[t] = mlp(relu(state), p, tm)[4]
// ---------------------------------------------------------------------------
__global__ __launch_bounds__(256) void out_kernel(
    const float* __restrict__ inputs,
    const float* __restrict__ traj,
    const float* __restrict__ W1, const float* __restrict__ b1,
    const float* __restrict__ W2, const float* __restrict__ b2,
    const float* __restrict__ W3, const float* __restrict__ b3,
    float* __restrict__ out)
{
    __shared__ float sW1[4 * HID];
    __shared__ float sb1[HID];
    __shared__ float sW2T[HID * HID];
    __shared__ float sb2[HID];
    __shared__ float sw3[HID];
    for (int i = threadIdx.x; i < 4 * HID; i += 256) sW1[i] = W1[i];
    for (int i = threadIdx.x; i < HID; i += 256) {
        sb1[i] = b1[i]; sb2[i] = b2[i]; sw3[i] = W3[i * 5 + 4];
    }
    for (int idx = threadIdx.x; idx < HID * HID; idx += 256) {
        int jj = idx >> 5, ii = idx & 31;
        sW2T[idx] = W2[ii * HID + jj];
    }
    __syncthreads();

    int t = blockIdx.x * 256 + threadIdx.x;
    if (t >= T_TOTAL) return;

    float2 st = ((const float2*)traj)[t];
    float s0 = fmaxf(st.x, 0.0f);
    float s1 = fmaxf(st.y, 0.0f);
    float p  = inputs[t * 5 + 2];
    float tm = inputs[t * 5 + 3];

    float h1[HID];
#pragma unroll
    for (int jj = 0; jj < HID; ++jj) {
        float pre = fmaf(s0, sW1[jj], fmaf(s1, sW1[HID + jj],
                    fmaf(p, sW1[2 * HID + jj],
                    fmaf(tm, sW1[3 * HID + jj], sb1[jj]))));
        h1[jj] = fast_tanh_clamp(pre);
    }
    float o = b3[4];
#pragma unroll 4
    for (int jj = 0; jj < HID; ++jj) {
        float a0 = sb2[jj], a1 = 0.f, a2 = 0.f, a3 = 0.f;
#pragma unroll
        for (int ii = 0; ii < HID; ii += 4) {
            a0 = fmaf(h1[ii + 0], sW2T[jj * HID + ii + 0], a0);
            a1 = fmaf(h1[ii + 1], sW2T[jj * HID + ii + 1], a1);
            a2 = fmaf(h1[ii + 2], sW2T[jj * HID + ii + 2], a2);
            a3 = fmaf(h1[ii + 3], sW2T[jj * HID + ii + 3], a3);
        }
        o = fmaf(fast_tanh_nc((a0 + a1) + (a2 + a3)), sw3[jj], o);
    }
    out[t] = o;
}

extern "C" void kernel_launch(void* const* d_in, const int* in_sizes, int n_in,
                              void* d_out, int out_size, void* d_ws, size_t ws_size,
                              hipStream_t stream) {
    (void)in_sizes; (void)n_in; (void)out_size; (void)ws_size;
    const float* inputs = (const float*)d_in[0];
    const float* lday   = (const float*)d_in[1];
    const float* W1     = (const float*)d_in[2];
    const float* b1     = (const float*)d_in[3];
    const float* W2     = (const float*)d_in[4];
    const float* b2     = (const float*)d_in[5];
    const float* W3     = (const float*)d_in[6];
    const float* b3     = (const float*)d_in[7];
    float* out  = (float*)d_out;
    float* traj = (float*)d_ws;                 // T*2 floats = 2 MB

    // small Parareal arrays live in d_out (scratch until out_kernel)
    // E = 3*WIN double2 = 96 KB at offset 0; icg = WIN float2 = 16 KB at +128 KB
    char* scr = (char*)d_out;
    double2* E  = (double2*)scr;
    float2* icg = (float2*)(scr + 131072);

    hipLaunchKernelGGL(init_kernel, dim3((WIN + 255) / 256), dim3(256), 0, stream,
                       inputs, icg);
    for (int k = 0; k < NSWEEP - 1; ++k) {
        hipLaunchKernelGGL(sweep_kernel, dim3(WIN), dim3(64), 0, stream,
                           inputs, lday, W1, b1, W2, b2, W3, b3, traj, icg, E);
        hipLaunchKernelGGL(correct_kernel, dim3(1), dim3(64), 0, stream,
                           inputs, E, icg);
    }
    // final sweep: trajectory becomes self-consistent with corrected ICs
    hipLaunchKernelGGL(sweep_kernel, dim3(WIN), dim3(64), 0, stream,
                       inputs, lday, W1, b1, W2, b2, W3, b3, traj, icg, E);
    hipLaunchKernelGGL(out_kernel, dim3((T_TOTAL + 255) / 256), dim3(256), 0, stream,
                       inputs, traj, W1, b1, W2, b2, W3, b3, out);
}